// Round 5
// baseline (5209.495 us; speedup 1.0000x reference)
//
#include <hip/hip_runtime.h>
#include <stdint.h>

// Problem constants
#define BB   128      // batch
#define LL   128      // latent dim
#define HH   1024     // hidden
#define G4   4096     // 4*H
#define TT   256      // time steps
#define PP   128      // output cols per step

#define NGB  64                  // gate blocks: 16 units each (64 weight rows)
#define NFB  8                   // fc blocks: 16 rows of W_fc each
#define NB   (NGB + NFB)

// HW_REG_XCC_ID = hwreg id 20, offset 0, size 32
#define XCC_HWREG 63508

typedef _Float16 half8  __attribute__((ext_vector_type(8)));
typedef float   floatx4 __attribute__((ext_vector_type(4)));

__device__ __forceinline__ float sigf(float x) {
  x = fminf(fmaxf(x, -30.f), 30.f);
  return 1.f / (1.f + __expf(-x));
}
__device__ __forceinline__ float tanhf_fast(float x) {
  x = fminf(fmaxf(x, -15.f), 15.f);
  float e = __expf(2.f * x);
  return (e - 1.f) / (e + 1.f);
}
__device__ __forceinline__ unsigned short f2h(float x) {
  _Float16 h = (_Float16)x;
  return __builtin_bit_cast(unsigned short, h);
}
// system-scope write-through h store: visible at LLC once vmcnt(0) drains
__device__ __forceinline__ void store_h(unsigned short* p, float x) {
  __hip_atomic_store(p, f2h(x), __ATOMIC_RELAXED, __HIP_MEMORY_SCOPE_SYSTEM);
}

// Flat monotonic grid barrier with full fences (startup only).
__device__ __forceinline__ void gridbar_flat(unsigned* bar, unsigned target) {
  __syncthreads();
  if (threadIdx.x == 0) {
    __threadfence();
    atomicAdd(bar, 1u);
    while (__hip_atomic_load(bar, __ATOMIC_RELAXED, __HIP_MEMORY_SCOPE_AGENT) < target)
      __builtin_amdgcn_s_sleep(1);
    __threadfence();
  }
  __syncthreads();
}

// Hierarchical per-step barrier: release = write-through stores + vmcnt(0)
// (proven R3/R4); acquire fence invalidates L1/L2 so cached A-loads see fresh h.
__device__ __forceinline__ void stepbar(unsigned* lbar, unsigned* gbar,
                                        unsigned lcnt, unsigned nldr, bool leader,
                                        unsigned s) {
  __syncthreads();
  if (threadIdx.x == 0) {
    asm volatile("s_waitcnt vmcnt(0)" ::: "memory");   // h stores ack'd at LLC
    __hip_atomic_fetch_add(lbar, 1u, __ATOMIC_RELAXED, __HIP_MEMORY_SCOPE_AGENT);
    if (leader) {
      while (__hip_atomic_load(lbar, __ATOMIC_RELAXED, __HIP_MEMORY_SCOPE_AGENT) < lcnt * s)
        __builtin_amdgcn_s_sleep(1);
      __hip_atomic_fetch_add(gbar, 1u, __ATOMIC_RELAXED, __HIP_MEMORY_SCOPE_AGENT);
    }
    while (__hip_atomic_load(gbar, __ATOMIC_RELAXED, __HIP_MEMORY_SCOPE_AGENT) < nldr * s)
      __builtin_amdgcn_s_sleep(1);
    __builtin_amdgcn_fence(__ATOMIC_ACQUIRE, "agent");  // inv L1/L2 before A reads
  }
  __syncthreads();
}

// gates0 = z @ w_ih^T + b_ih + b_hh   (step-0 gates; h0=c0=0, x=0 for t>=1)
__global__ void prep_gates0(const float* __restrict__ z, const float* __restrict__ w_ih,
                            const float* __restrict__ b_ih, const float* __restrict__ b_hh,
                            float* __restrict__ g0) {
  int j = blockIdx.x;     // 0..4095
  int b = threadIdx.x;    // 0..127
  const float* zr = z + b * LL;
  const float* wr = w_ih + (size_t)j * LL;
  float s = 0.f;
#pragma unroll 4
  for (int k = 0; k < LL; ++k) s += zr[k] * wr[k];
  g0[(size_t)b * G4 + j] = s + b_ih[j] + b_hh[j];
}

// fp16 weights, plain row-major (no swizzle — weights live in VGPRs now).
// Gate block bid rows: [i0..15 | g0..15 | f0..15 | o0..15] for units bid*16+nl.
__global__ void prep_weights(const float* __restrict__ w_hh, const float* __restrict__ W_fc,
                             unsigned short* __restrict__ wbuf) {
  int R = blockIdx.x;                 // 0..4223
  const float* src;
  if (R < NGB * 64) {
    int bid = R >> 6, rr = R & 63, tile = rr >> 4, nl = rr & 15;
    int g = (tile == 0) ? 0 : (tile == 1) ? 2 : (tile == 2) ? 1 : 3;  // i,g,f,o
    src = w_hh + (size_t)(g * HH + bid * 16 + nl) * HH;
  } else {
    src = W_fc + (size_t)(R - NGB * 64) * HH;
  }
  unsigned short* dst = wbuf + (size_t)R * HH;
  for (int k = threadIdx.x; k < HH; k += blockDim.x) {
    _Float16 v = (_Float16)src[k];
    dst[k] = __builtin_bit_cast(unsigned short, v);
  }
}

// K=1024 MFMA pass, B entirely in registers. A streamed with a 16-deep
// register ring of cached global loads (compiler-managed vmcnt).
// flat idx = kc*MT + mt; A-frag offset (half8) = mt*2048 + kc*4.
template <int MT, int NT>
__device__ __forceinline__ void gemm_regB(const half8* __restrict__ hb8, int aoffbase,
                                          const half8 (&b)[NT][32],
                                          floatx4 (&acc)[MT][NT]) {
  half8 ap[16];
#pragma unroll
  for (int x = 0; x < 16; ++x)
    ap[x] = hb8[aoffbase + (x % MT) * 2048 + (x / MT) * 4];
#pragma unroll
  for (int kc = 0; kc < 32; ++kc) {
#pragma unroll
    for (int mt = 0; mt < MT; ++mt) {
      const int idx = kc * MT + mt;
      half8 a = ap[idx & 15];
      if (idx + 16 < 32 * MT)
        ap[idx & 15] = hb8[aoffbase + ((idx + 16) % MT) * 2048 + ((idx + 16) / MT) * 4];
#pragma unroll
      for (int nt = 0; nt < NT; ++nt)
        acc[mt][nt] = __builtin_amdgcn_mfma_f32_16x16x32_f16(a, b[nt][kc], acc[mt][nt], 0, 0, 0);
    }
  }
}

#define SX(m, g, u) sX[(m) * 69 + (g) * 17 + (u)]

__global__ __launch_bounds__(256, 1) void lstm_persist(
    const float* __restrict__ g0,
    const unsigned short* __restrict__ wbuf,
    const float* __restrict__ b_ih, const float* __restrict__ b_hh,
    const float* __restrict__ b_fc,
    float* __restrict__ out,
    unsigned short* __restrict__ hbuf,   // [2][B][H] fp16 double buffer
    unsigned* __restrict__ ctl) {
  __shared__ float sX[128 * 69];         // gate-exchange scratch (~34.5 KiB)
  const int tid  = threadIdx.x;
  const int wv   = tid >> 6;
  const int lane = tid & 63;
  const int quad = lane >> 4;
  const int l15  = lane & 15;
  const int bid  = blockIdx.x;
  const bool isg = bid < NGB;

  unsigned* census = ctl;            // 8 uints
  unsigned* fbar   = ctl + 32;
  unsigned* gbar   = ctl + 64;
  // per-XCD lines at ctl + 128 + x*32

  unsigned myx = 0, rank = 0;
  if (tid == 0) {
    myx  = __builtin_amdgcn_s_getreg(XCC_HWREG) & 7u;
    rank = atomicAdd(&census[myx], 1u);
  }

  const floatx4 z4 = {0.f, 0.f, 0.f, 0.f};
  const half8* wb8 = (const half8*)wbuf;

  if (isg) {
    const int i = wv >> 1;          // m-half: rows [i*64, i*64+64)
    const int j = wv & 1;           // n-half: gates {i,g} (j=0) / {f,o} (j=1)
    const int u = bid * 16 + l15;   // unit this lane owns in epilogue

    // ---- B into registers: 2 n-tiles x 32 k-chunks = 256 VGPRs, loaded once
    half8 b[2][32];
#pragma unroll
    for (int nt = 0; nt < 2; ++nt) {
      const int row = bid * 64 + j * 32 + nt * 16 + l15;
      const int base = row * 128 + quad;
#pragma unroll
      for (int kc = 0; kc < 32; ++kc) b[nt][kc] = wb8[base + kc * 4];
    }
    // biases for this wave's two gates (gate idx = j*2+nt; order i,g,f,o)
    float bias0, bias1;
    if (j == 0) { bias0 = b_ih[u]          + b_hh[u];               // i
                  bias1 = b_ih[2*HH + u]   + b_hh[2*HH + u]; }      // g
    else        { bias0 = b_ih[HH + u]     + b_hh[HH + u];          // f
                  bias1 = b_ih[3*HH + u]   + b_hh[3*HH + u]; }      // o

    // epilogue ownership: wave wv owns m-rows [wv*32, wv*32+32)
    // lane: u = l15, msub = quad, m = wv*32 + msub*8 + r (r 0..7)
    float c[8];
#pragma unroll
    for (int r = 0; r < 8; ++r) c[r] = 0.f;

    // ---- t = 0: gates precomputed in g0; c_prev = 0
#pragma unroll
    for (int r = 0; r < 8; ++r) {
      const int m = wv * 32 + quad * 8 + r;
      const float* gr = g0 + (size_t)m * G4;
      float iv = gr[u], gv = gr[2 * HH + u], ov = gr[3 * HH + u];
      float ct = sigf(iv) * tanhf_fast(gv);
      c[r] = ct;
      store_h(hbuf + (size_t)m * HH + u, sigf(ov) * tanhf_fast(ct));
    }
    gridbar_flat(fbar, NB);   // publishes census, syncs t=0

    unsigned lcnt = 0, nldr = 0; unsigned* lbar = nullptr; bool leader = false;
    if (tid == 0) {
      lcnt = __hip_atomic_load(&census[myx], __ATOMIC_RELAXED, __HIP_MEMORY_SCOPE_AGENT);
      for (int x = 0; x < 8; ++x)
        nldr += (__hip_atomic_load(&census[x], __ATOMIC_RELAXED, __HIP_MEMORY_SCOPE_AGENT) > 0);
      lbar = ctl + 128 + myx * 32;
      leader = (rank == 0);
    }

    const int aoffbase = (i * 64 + l15) * 128 + quad;

    for (int t = 1; t < TT; ++t) {
      const half8* hb8 = (const half8*)(hbuf + (size_t)((t - 1) & 1) * BB * HH);
      unsigned short* hw = hbuf + (size_t)(t & 1) * BB * HH;
      floatx4 acc[4][2] = {{z4, z4}, {z4, z4}, {z4, z4}, {z4, z4}};
      gemm_regB<4, 2>(hb8, aoffbase, b, acc);
      // publish pre-activations to LDS: SX[m][gate][u]
#pragma unroll
      for (int mt = 0; mt < 4; ++mt)
#pragma unroll
        for (int r = 0; r < 4; ++r) {
          const int m = i * 64 + mt * 16 + quad * 4 + r;
          SX(m, j * 2 + 0, l15) = acc[mt][0][r] + bias0;
          SX(m, j * 2 + 1, l15) = acc[mt][1][r] + bias1;
        }
      __syncthreads();
      // cell update on owned (m, u) cells
#pragma unroll
      for (int r = 0; r < 8; ++r) {
        const int m = wv * 32 + quad * 8 + r;
        float iv = sigf(SX(m, 0, l15));
        float gv = tanhf_fast(SX(m, 1, l15));
        float fv = sigf(SX(m, 2, l15));
        float ov = sigf(SX(m, 3, l15));
        float ct = fv * c[r] + iv * gv;
        c[r] = ct;
        store_h(hw + (size_t)m * HH + u, ov * tanhf_fast(ct));
      }
      stepbar(lbar, gbar, lcnt, nldr, leader, (unsigned)t);
    }
  } else {
    // fc block: y_{t-1} = h_{t-1} @ W_fc^T + b_fc, overlapped with step-t gates
    const int fb = bid - NGB;
    const int pcol = fb * 16 + l15;
    const float biasf = b_fc[pcol];

    half8 b[1][32];
    {
      const int row = NGB * 64 + fb * 16 + l15;
      const int base = row * 128 + quad;
#pragma unroll
      for (int kc = 0; kc < 32; ++kc) b[0][kc] = wb8[base + kc * 4];
    }

    gridbar_flat(fbar, NB);

    unsigned lcnt = 0, nldr = 0; unsigned* lbar = nullptr; bool leader = false;
    if (tid == 0) {
      lcnt = __hip_atomic_load(&census[myx], __ATOMIC_RELAXED, __HIP_MEMORY_SCOPE_AGENT);
      for (int x = 0; x < 8; ++x)
        nldr += (__hip_atomic_load(&census[x], __ATOMIC_RELAXED, __HIP_MEMORY_SCOPE_AGENT) > 0);
      lbar = ctl + 128 + myx * 32;
      leader = (rank == 0);
    }

    const int aoffbase = (wv * 32 + l15) * 128 + quad;

    for (int t = 1; t <= TT; ++t) {
      const half8* hb8 = (const half8*)(hbuf + (size_t)((t - 1) & 1) * BB * HH);
      floatx4 acc[2][1] = {{z4}, {z4}};
      gemm_regB<2, 1>(hb8, aoffbase, b, acc);
#pragma unroll
      for (int mt = 0; mt < 2; ++mt)
#pragma unroll
        for (int r = 0; r < 4; ++r) {
          const int m = wv * 32 + mt * 16 + quad * 4 + r;
          out[(size_t)m * (TT * PP) + (size_t)(t - 1) * PP + pcol] = acc[mt][0][r] + biasf;
        }
      if (t < TT) stepbar(lbar, gbar, lcnt, nldr, leader, (unsigned)t);
    }
  }
}

extern "C" void kernel_launch(void* const* d_in, const int* in_sizes, int n_in,
                              void* d_out, int out_size, void* d_ws, size_t ws_size,
                              hipStream_t stream) {
  const float* z    = (const float*)d_in[1];
  const float* w_ih = (const float*)d_in[2];
  const float* w_hh = (const float*)d_in[3];
  const float* b_ih = (const float*)d_in[4];
  const float* b_hh = (const float*)d_in[5];
  const float* W_fc = (const float*)d_in[6];
  const float* b_fc = (const float*)d_in[7];
  float* out = (float*)d_out;

  char* ws = (char*)d_ws;
  unsigned*       ctl  = (unsigned*)ws;                                        // 4 KiB
  unsigned short* hbuf = (unsigned short*)(ws + 4096);                         // 512 KiB
  float*          g0   = (float*)(ws + 4096 + (size_t)2 * BB * HH * 2);        // 2 MiB
  unsigned short* wbuf = (unsigned short*)(ws + 4096 + (size_t)2 * BB * HH * 2
                                              + (size_t)BB * G4 * 4);          // 8.25 MiB

  hipMemsetAsync(ctl, 0, 4096, stream);
  prep_gates0 <<<dim3(G4), dim3(BB), 0, stream>>>(z, w_ih, b_ih, b_hh, g0);
  prep_weights<<<dim3(NGB * 64 + NFB * 16), dim3(256), 0, stream>>>(w_hh, W_fc, wbuf);
  lstm_persist<<<dim3(NB), dim3(256), 0, stream>>>(g0, wbuf, b_ih, b_hh, b_fc,
                                                   out, hbuf, ctl);
}

// Round 6
// 3295.868 us; speedup vs baseline: 1.5806x; 1.5806x over previous
//
#include <hip/hip_runtime.h>
#include <stdint.h>

// Problem constants
#define BB   128      // batch
#define LL   128      // latent dim
#define HH   1024     // hidden
#define G4   4096     // 4*H
#define TT   256      // time steps
#define PP   128      // output cols per step

#define NGB  64                  // gate blocks: 16 units each (64 weight rows)
#define NFB  8                   // fc blocks: 16 rows of W_fc each
#define NB   (NGB + NFB)

#define STAGE_H8 16384           // one staged h image = BB*HH halves = 16384 half8

// HW_REG_XCC_ID = hwreg id 20, offset 0, size 32
#define XCC_HWREG 63508

typedef _Float16 half8  __attribute__((ext_vector_type(8)));
typedef float   floatx4 __attribute__((ext_vector_type(4)));

__device__ __forceinline__ float sigf(float x) {
  x = fminf(fmaxf(x, -30.f), 30.f);
  return 1.f / (1.f + __expf(-x));
}
__device__ __forceinline__ float tanhf_fast(float x) {
  x = fminf(fmaxf(x, -15.f), 15.f);
  float e = __expf(2.f * x);
  return (e - 1.f) / (e + 1.f);
}
__device__ __forceinline__ unsigned short f2h(float x) {
  _Float16 h = (_Float16)x;
  return __builtin_bit_cast(unsigned short, h);
}
// system-scope write-through h store: visible at LLC once vmcnt(0) drains
__device__ __forceinline__ void store_h(unsigned short* p, float x) {
  __hip_atomic_store(p, f2h(x), __ATOMIC_RELAXED, __HIP_MEMORY_SCOPE_SYSTEM);
}
// system-scope 16B load (bypasses L1+L2, reads coherent LLC) — copy phase only.
__device__ __forceinline__ void load_sys(half8& d, const half8* p) {
  asm volatile("global_load_dwordx4 %0, %1, off sc0 sc1" : "=v"(d) : "v"(p));
}
__device__ __forceinline__ void vmcnt0() {
  asm volatile("s_waitcnt vmcnt(0)" ::: "memory");
}

// Flat monotonic grid barrier with full fences (startup only).
__device__ __forceinline__ void gridbar_flat(unsigned* bar, unsigned target) {
  __syncthreads();
  if (threadIdx.x == 0) {
    __threadfence();
    atomicAdd(bar, 1u);
    while (__hip_atomic_load(bar, __ATOMIC_RELAXED, __HIP_MEMORY_SCOPE_AGENT) < target)
      __builtin_amdgcn_s_sleep(1);
    __threadfence();
  }
  __syncthreads();
}

// gates0 = z @ w_ih^T + b_ih + b_hh   (step-0 gates; h0=c0=0, x=0 for t>=1)
__global__ void prep_gates0(const float* __restrict__ z, const float* __restrict__ w_ih,
                            const float* __restrict__ b_ih, const float* __restrict__ b_hh,
                            float* __restrict__ g0) {
  int j = blockIdx.x;     // 0..4095
  int b = threadIdx.x;    // 0..127
  const float* zr = z + b * LL;
  const float* wr = w_ih + (size_t)j * LL;
  float s = 0.f;
#pragma unroll 4
  for (int k = 0; k < LL; ++k) s += zr[k] * wr[k];
  g0[(size_t)b * G4 + j] = s + b_ih[j] + b_hh[j];
}

// fp16 weights in the LDS layout (R2-proven): gate block bid rows
// (tile*16+nl), tile 0..3 = gates i,g,f,o of unit bid*16+nl; k-chunks
// XOR-swizzled by (nl&7) to break LDS bank conflicts.
__global__ void prep_weights(const float* __restrict__ w_hh, const float* __restrict__ W_fc,
                             unsigned short* __restrict__ wbuf) {
  int R = blockIdx.x;                 // 0..4223
  const float* src; int rsw;
  if (R < NGB * 64) {
    int bid = R >> 6, rr = R & 63, tile = rr >> 4, nl = rr & 15;
    int g = (tile == 0) ? 0 : (tile == 1) ? 2 : (tile == 2) ? 1 : 3;  // i,g,f,o
    src = w_hh + (size_t)(g * HH + bid * 16 + nl) * HH;
    rsw = nl & 7;
  } else {
    int p = R - NGB * 64;
    src = W_fc + (size_t)p * HH;
    rsw = p & 7;
  }
  unsigned short* dst = wbuf + (size_t)R * HH;
  for (int k = threadIdx.x; k < HH; k += blockDim.x) {
    int dk = (((k >> 3) ^ rsw) << 3) | (k & 7);
    _Float16 v = (_Float16)src[k];
    dst[dk] = __builtin_bit_cast(unsigned short, v);
  }
}

// K=1024 MFMA pass (R2-proven): C[2 x NT], A from staged (plain cached loads,
// 8-deep ring per m-stream, compiler-managed waits), B from LDS (swizzled).
template <int NT>
__device__ __forceinline__ void gemm2xNT(const half8* __restrict__ hb8,
                                         const half8* __restrict__ w8,
                                         int abase0, int abase1,
                                         int quad, int rsw, int l15,
                                         floatx4 acc[2][NT]) {
  half8 ap0[8], ap1[8];
#pragma unroll
  for (int i = 0; i < 8; ++i) { ap0[i] = hb8[abase0 + i * 4]; ap1[i] = hb8[abase1 + i * 4]; }
#pragma unroll
  for (int kc = 0; kc < 32; ++kc) {
    half8 a0 = ap0[kc & 7], a1 = ap1[kc & 7];
    if (kc < 24) {
      ap0[kc & 7] = hb8[abase0 + (kc + 8) * 4];
      ap1[kc & 7] = hb8[abase1 + (kc + 8) * 4];
    }
    int sw = (kc * 4 + quad) ^ rsw;
#pragma unroll
    for (int nt = 0; nt < NT; ++nt) {
      half8 b = w8[(nt * 16 + l15) * 128 + sw];
      acc[0][nt] = __builtin_amdgcn_mfma_f32_16x16x32_f16(a0, b, acc[0][nt], 0, 0, 0);
      acc[1][nt] = __builtin_amdgcn_mfma_f32_16x16x32_f16(a1, b, acc[1][nt], 0, 0, 0);
    }
  }
}

// Copy my slice of h (LLC) into this XCD's staged slot (plain stores -> local L2).
__device__ __forceinline__ void copy_slice(const half8* __restrict__ src8,
                                           half8* __restrict__ dst8,
                                           int c0, int c1, int tid) {
  for (int cb = c0 + tid; cb < c1; cb += 2560) {
    half8 tmp[10];
#pragma unroll
    for (int i = 0; i < 10; ++i) { int c = cb + i * 256; if (c < c1) load_sys(tmp[i], src8 + c); }
    vmcnt0();
#pragma unroll
    for (int i = 0; i < 10; ++i) { int c = cb + i * 256; if (c < c1) dst8[c] = tmp[i]; }
  }
}

__global__ __launch_bounds__(256, 1) void lstm_persist(
    const float* __restrict__ g0,
    const unsigned short* __restrict__ wbuf,
    const float* __restrict__ b_ih, const float* __restrict__ b_hh,
    const float* __restrict__ b_fc,
    float* __restrict__ out,
    unsigned short* __restrict__ hbuf,     // [2][B][H] fp16, LLC-coherent canonical h
    unsigned short* __restrict__ staged,   // [8 xcd][4 ring][B][H] fp16, L2-local copies
    unsigned* __restrict__ ctl) {
  extern __shared__ __align__(16) unsigned short sW[];   // 128 KiB (gate) / 32 KiB (fc)
  __shared__ unsigned sMeta[4];                          // lcnt, nldr, rank, myx
  const int tid  = threadIdx.x;
  const int wv   = tid >> 6;
  const int lane = tid & 63;
  const int quad = lane >> 4;
  const int l15  = lane & 15;
  const int bid  = blockIdx.x;
  const bool isg = bid < NGB;
  const int rsw  = l15 & 7;

  unsigned* census = ctl;            // 8 uints
  unsigned* fbar   = ctl + 32;       // startup barrier
  unsigned* gbar   = ctl + 64;       // global step counter
  // lbar  (GEMM barrier arrivals)  at ctl + 128 + x*32
  // lbar2 (copy barrier arrivals)  at ctl + 512 + x*32

  unsigned myx0 = 0, rank0 = 0;
  if (tid == 0) {
    myx0  = __builtin_amdgcn_s_getreg(XCC_HWREG) & 7u;
    rank0 = atomicAdd(&census[myx0], 1u);
  }

  { // stage this block's weight slice into LDS
    const uint4* s4 = (const uint4*)(wbuf +
        (size_t)(isg ? bid * 64 : NGB * 64 + (bid - NGB) * 16) * HH);
    uint4* d4 = (uint4*)sW;
    const int n16 = (isg ? 64 * HH : 16 * HH) / 8;
    for (int i = tid; i < n16; i += 256) d4[i] = s4[i];
  }
  __syncthreads();
  const half8* w8 = (const half8*)sW;
  const floatx4 z4 = {0.f, 0.f, 0.f, 0.f};

  // ---- t = 0 (gate blocks): gates precomputed in g0; c_prev = 0
  float c[2][4] = {{0, 0, 0, 0}, {0, 0, 0, 0}};
  const int u = isg ? (bid * 16 + l15) : 0;
  if (isg) {
#pragma unroll
    for (int mt = 0; mt < 2; ++mt)
#pragma unroll
      for (int r = 0; r < 4; ++r) {
        const int m = wv * 32 + mt * 16 + quad * 4 + r;
        const float* gr = g0 + (size_t)m * G4;
        float iv = gr[u], gv = gr[2 * HH + u], ov = gr[3 * HH + u];
        float ct = sigf(iv) * tanhf_fast(gv);
        c[mt][r] = ct;
        store_h(hbuf + (size_t)m * HH + u, sigf(ov) * tanhf_fast(ct));
      }
  }
  gridbar_flat(fbar, NB);   // h[0] visible + census complete

  if (tid == 0) {
    unsigned lc = __hip_atomic_load(&census[myx0], __ATOMIC_RELAXED, __HIP_MEMORY_SCOPE_AGENT);
    unsigned nl = 0;
    for (int x = 0; x < 8; ++x)
      nl += (__hip_atomic_load(&census[x], __ATOMIC_RELAXED, __HIP_MEMORY_SCOPE_AGENT) > 0);
    sMeta[0] = lc; sMeta[1] = nl; sMeta[2] = rank0; sMeta[3] = myx0;
  }
  __syncthreads();
  const unsigned lcnt = sMeta[0], nldr = sMeta[1], rank = sMeta[2], myx = sMeta[3];
  const bool leader = (rank == 0);
  unsigned* lbar  = ctl + 128 + myx * 32;
  unsigned* lbar2 = ctl + 512 + myx * 32;
  // copy slice bounds (16B chunks of one 256 KB h image)
  const int c0 = (int)((16384u * rank) / lcnt);
  const int c1 = (int)((16384u * (rank + 1)) / lcnt);
  half8* sbase = (half8*)staged + (size_t)myx * 4 * STAGE_H8;

  if (isg) {
    const float bi = b_ih[u]          + b_hh[u];
    const float bg = b_ih[2*HH + u]   + b_hh[2*HH + u];
    const float bf = b_ih[HH + u]     + b_hh[HH + u];
    const float bo = b_ih[3*HH + u]   + b_hh[3*HH + u];

    const int abase0 = (wv * 32 +      l15) * 128 + quad;
    const int abase1 = (wv * 32 + 16 + l15) * 128 + quad;

    for (int t = 1; t < TT; ++t) {
      const half8* src8 = (const half8*)(hbuf + (size_t)((t - 1) & 1) * BB * HH);
      half8* slot = sbase + (size_t)((t - 1) & 3) * STAGE_H8;
      unsigned short* hw = hbuf + (size_t)(t & 1) * BB * HH;

      // 1) cooperative LLC->L2 copy of h[t-1]
      copy_slice(src8, slot, c0, c1, tid);
      // 2) per-XCD copy barrier
      vmcnt0();
      __syncthreads();
      if (tid == 0) {
        __hip_atomic_fetch_add(lbar2, 1u, __ATOMIC_RELAXED, __HIP_MEMORY_SCOPE_AGENT);
        while (__hip_atomic_load(lbar2, __ATOMIC_RELAXED, __HIP_MEMORY_SCOPE_AGENT) < lcnt * (unsigned)t)
          __builtin_amdgcn_s_sleep(1);
      }
      __syncthreads();
      // 3) GEMM from L2-local staged copy (plain cached loads)
      floatx4 acc[2][4] = {{z4, z4, z4, z4}, {z4, z4, z4, z4}};
      gemm2xNT<4>(slot, w8, abase0, abase1, quad, rsw, l15, acc);
      // 4) cell update + system write-through h[t]
#pragma unroll
      for (int mt = 0; mt < 2; ++mt)
#pragma unroll
        for (int r = 0; r < 4; ++r) {
          float iv = sigf(acc[mt][0][r] + bi);
          float gv = tanhf_fast(acc[mt][1][r] + bg);
          float fv = sigf(acc[mt][2][r] + bf);
          float ov = sigf(acc[mt][3][r] + bo);
          float ct = fv * c[mt][r] + iv * gv;
          c[mt][r] = ct;
          const int m = wv * 32 + mt * 16 + quad * 4 + r;
          store_h(hw + (size_t)m * HH + u, ov * tanhf_fast(ct));
        }
      // 5) global step barrier (fence-free; per-wave drain)
      vmcnt0();
      __syncthreads();
      if (tid == 0) {
        __hip_atomic_fetch_add(lbar, 1u, __ATOMIC_RELAXED, __HIP_MEMORY_SCOPE_AGENT);
        if (leader) {
          while (__hip_atomic_load(lbar, __ATOMIC_RELAXED, __HIP_MEMORY_SCOPE_AGENT) < lcnt * (unsigned)t)
            __builtin_amdgcn_s_sleep(1);
          __hip_atomic_fetch_add(gbar, 1u, __ATOMIC_RELAXED, __HIP_MEMORY_SCOPE_AGENT);
        }
        while (__hip_atomic_load(gbar, __ATOMIC_RELAXED, __HIP_MEMORY_SCOPE_AGENT) < nldr * (unsigned)t)
          __builtin_amdgcn_s_sleep(1);
      }
      __syncthreads();
    }
    // final copy (t = TT) so fc blocks can project y[TT-1]
    {
      const half8* src8 = (const half8*)(hbuf + (size_t)((TT - 1) & 1) * BB * HH);
      half8* slot = sbase + (size_t)((TT - 1) & 3) * STAGE_H8;
      copy_slice(src8, slot, c0, c1, tid);
      vmcnt0();
      __syncthreads();
      if (tid == 0)
        __hip_atomic_fetch_add(lbar2, 1u, __ATOMIC_RELAXED, __HIP_MEMORY_SCOPE_AGENT);
    }
  } else {
    // fc block: y_{t-1} = h_{t-1} @ W_fc^T + b_fc
    const int fb = bid - NGB;
    const int pcol = fb * 16 + l15;
    const float biasf = b_fc[pcol];
    const int abase0 = ((wv * 2 + 0) * 16 + l15) * 128 + quad;
    const int abase1 = ((wv * 2 + 1) * 16 + l15) * 128 + quad;

    for (int t = 1; t <= TT; ++t) {
      const half8* src8 = (const half8*)(hbuf + (size_t)((t - 1) & 1) * BB * HH);
      half8* slot = sbase + (size_t)((t - 1) & 3) * STAGE_H8;

      copy_slice(src8, slot, c0, c1, tid);
      vmcnt0();
      __syncthreads();
      if (tid == 0) {
        __hip_atomic_fetch_add(lbar2, 1u, __ATOMIC_RELAXED, __HIP_MEMORY_SCOPE_AGENT);
        while (__hip_atomic_load(lbar2, __ATOMIC_RELAXED, __HIP_MEMORY_SCOPE_AGENT) < lcnt * (unsigned)t)
          __builtin_amdgcn_s_sleep(1);
      }
      __syncthreads();

      floatx4 acc[2][1] = {{z4}, {z4}};
      gemm2xNT<1>(slot, w8, abase0, abase1, quad, rsw, l15, acc);
#pragma unroll
      for (int mt = 0; mt < 2; ++mt)
#pragma unroll
        for (int r = 0; r < 4; ++r) {
          const int m = wv * 32 + mt * 16 + quad * 4 + r;
          out[(size_t)m * (TT * PP) + (size_t)(t - 1) * PP + pcol] = acc[mt][0][r] + biasf;
        }

      if (t < TT) {
        vmcnt0();
        __syncthreads();
        if (tid == 0) {
          __hip_atomic_fetch_add(lbar, 1u, __ATOMIC_RELAXED, __HIP_MEMORY_SCOPE_AGENT);
          if (leader) {
            while (__hip_atomic_load(lbar, __ATOMIC_RELAXED, __HIP_MEMORY_SCOPE_AGENT) < lcnt * (unsigned)t)
              __builtin_amdgcn_s_sleep(1);
            __hip_atomic_fetch_add(gbar, 1u, __ATOMIC_RELAXED, __HIP_MEMORY_SCOPE_AGENT);
          }
          while (__hip_atomic_load(gbar, __ATOMIC_RELAXED, __HIP_MEMORY_SCOPE_AGENT) < nldr * (unsigned)t)
            __builtin_amdgcn_s_sleep(1);
        }
        __syncthreads();
      }
    }
  }
}

extern "C" void kernel_launch(void* const* d_in, const int* in_sizes, int n_in,
                              void* d_out, int out_size, void* d_ws, size_t ws_size,
                              hipStream_t stream) {
  const float* z    = (const float*)d_in[1];
  const float* w_ih = (const float*)d_in[2];
  const float* w_hh = (const float*)d_in[3];
  const float* b_ih = (const float*)d_in[4];
  const float* b_hh = (const float*)d_in[5];
  const float* W_fc = (const float*)d_in[6];
  const float* b_fc = (const float*)d_in[7];
  float* out = (float*)d_out;

  // workspace layout (~19.3 MiB)
  char* ws = (char*)d_ws;
  unsigned*       ctl    = (unsigned*)ws;                                 // 4 KiB
  unsigned short* hbuf   = (unsigned short*)(ws + 4096);                  // 512 KiB
  float*          g0     = (float*)(ws + 4096 + (size_t)2*BB*HH*2);       // 2 MiB
  unsigned short* wbuf   = (unsigned short*)(ws + 4096 + (size_t)2*BB*HH*2
                                                + (size_t)BB*G4*4);       // 8.25 MiB
  unsigned short* staged = (unsigned short*)(ws + 4096 + (size_t)2*BB*HH*2
                                                + (size_t)BB*G4*4
                                                + (size_t)(NGB*64 + NFB*16)*HH*2); // 8 MiB

  (void)hipFuncSetAttribute(reinterpret_cast<const void*>(lstm_persist),
                            hipFuncAttributeMaxDynamicSharedMemorySize, 160 * 1024);

  hipMemsetAsync(ctl, 0, 4096, stream);
  prep_gates0 <<<dim3(G4), dim3(BB), 0, stream>>>(z, w_ih, b_ih, b_hh, g0);
  prep_weights<<<dim3(NGB * 64 + NFB * 16), dim3(256), 0, stream>>>(w_hh, W_fc, wbuf);
  lstm_persist<<<dim3(NB), dim3(256), 128 * 1024, stream>>>(g0, wbuf, b_ih, b_hh, b_fc,
                                                            out, hbuf, staged, ctl);
}

// Round 8
// 3193.320 us; speedup vs baseline: 1.6314x; 1.0321x over previous
//
#include <hip/hip_runtime.h>
#include <stdint.h>

// Problem constants
#define BB   128      // batch
#define LL   128      // latent dim
#define HH   1024     // hidden
#define G4   4096     // 4*H
#define TT   256      // time steps
#define PP   128      // output cols per step

#define NGB  64                  // gate blocks: 16 units each (64 weight rows)
#define NFB  8                   // fc blocks: 16 rows of W_fc each
#define NB   (NGB + NFB)

typedef _Float16 half8  __attribute__((ext_vector_type(8)));
typedef float   floatx4 __attribute__((ext_vector_type(4)));
typedef unsigned int uint4v __attribute__((ext_vector_type(4)));

__device__ __forceinline__ float sigf(float x) {
  x = fminf(fmaxf(x, -30.f), 30.f);
  return 1.f / (1.f + __expf(-x));
}
__device__ __forceinline__ float tanhf_fast(float x) {
  x = fminf(fmaxf(x, -15.f), 15.f);
  float e = __expf(2.f * x);
  return (e - 1.f) / (e + 1.f);
}
__device__ __forceinline__ unsigned short f2h(float x) {
  _Float16 h = (_Float16)x;
  return __builtin_bit_cast(unsigned short, h);
}
// system-scope write-through h store (2B; t=0 only): visible at LLC after vmcnt(0)
__device__ __forceinline__ void store_h(unsigned short* p, float x) {
  __hip_atomic_store(p, f2h(x), __ATOMIC_RELAXED, __HIP_MEMORY_SCOPE_SYSTEM);
}
// system-scope 16B write-through store (epilogue bulk path)
__device__ __forceinline__ void store_sys16(unsigned short* p, uint4v v) {
  asm volatile("global_store_dwordx4 %0, %1, off sc0 sc1" :: "v"(p), "v"(v) : "memory");
}
// system-scope 16B load: bypasses L1+L2, reads coherent LLC. NOT tracked by the
// compiler's waitcnt pass — pair every consumer with waitv2<K>() below.
__device__ __forceinline__ void load_sys(half8& d, const half8* p) {
  asm volatile("global_load_dwordx4 %0, %1, off sc0 sc1" : "=v"(d) : "v"(p));
}
template <int K>
__device__ __forceinline__ void waitv2(half8& a, half8& b) {
  asm volatile("s_waitcnt vmcnt(%2)" : "+v"(a), "+v"(b) : "n"(K));
}
__device__ __forceinline__ void vmcnt0() {
  asm volatile("s_waitcnt vmcnt(0)" ::: "memory");
}

// Wait until all 72 producer flags reach s. One vector gather per iteration:
// lane i polls flag[i] (128B-padded lines); lanes 0..7 also poll flag[64+i].
__device__ __forceinline__ void poll_flags(const unsigned* flags, unsigned s, int lane) {
  const unsigned* p1 = flags + (size_t)lane * 32;
  const unsigned* p2 = flags + (size_t)(64 + (lane & 7)) * 32;
  for (;;) {
    unsigned v1 = __hip_atomic_load(p1, __ATOMIC_RELAXED, __HIP_MEMORY_SCOPE_AGENT);
    unsigned v2 = (lane < 8)
        ? __hip_atomic_load(p2, __ATOMIC_RELAXED, __HIP_MEMORY_SCOPE_AGENT) : s;
    if (__ballot((v1 >= s) && (v2 >= s)) == ~0ull) break;
    __builtin_amdgcn_s_sleep(1);
  }
  asm volatile("" ::: "memory");   // no hoisting of A-loads above the poll
}

// gates0 = z @ w_ih^T + b_ih + b_hh   (step-0 gates; h0=c0=0, x=0 for t>=1)
__global__ void prep_gates0(const float* __restrict__ z, const float* __restrict__ w_ih,
                            const float* __restrict__ b_ih, const float* __restrict__ b_hh,
                            float* __restrict__ g0) {
  int j = blockIdx.x;     // 0..4095
  int b = threadIdx.x;    // 0..127
  const float* zr = z + b * LL;
  const float* wr = w_ih + (size_t)j * LL;
  float s = 0.f;
#pragma unroll 4
  for (int k = 0; k < LL; ++k) s += zr[k] * wr[k];
  g0[(size_t)b * G4 + j] = s + b_ih[j] + b_hh[j];
}

// fp16 weights in the R2-proven LDS layout: gate block bid rows (tile*16+nl),
// tile 0..3 = gates i,g,f,o of unit bid*16+nl; k-chunks XOR-swizzled by (nl&7).
__global__ void prep_weights(const float* __restrict__ w_hh, const float* __restrict__ W_fc,
                             unsigned short* __restrict__ wbuf) {
  int R = blockIdx.x;                 // 0..4223
  const float* src; int rsw;
  if (R < NGB * 64) {
    int bid = R >> 6, rr = R & 63, tile = rr >> 4, nl = rr & 15;
    int g = (tile == 0) ? 0 : (tile == 1) ? 2 : (tile == 2) ? 1 : 3;  // i,g,f,o
    src = w_hh + (size_t)(g * HH + bid * 16 + nl) * HH;
    rsw = nl & 7;
  } else {
    int p = R - NGB * 64;
    src = W_fc + (size_t)p * HH;
    rsw = p & 7;
  }
  unsigned short* dst = wbuf + (size_t)R * HH;
  for (int k = threadIdx.x; k < HH; k += blockDim.x) {
    int dk = (((k >> 3) ^ rsw) << 3) | (k & 7);
    _Float16 v = (_Float16)src[k];
    dst[dk] = __builtin_bit_cast(unsigned short, v);
  }
}

// K=1024 MFMA pass (R4-proven): A LLC-direct with 16-deep x2 manual-vmcnt ring,
// B from LDS (swizzled).
template <int KC, int NT>
__device__ __forceinline__ void kstep(const half8* a0p, const half8* a1p,
                                      const half8* __restrict__ w8,
                                      half8 (&ap0)[16], half8 (&ap1)[16],
                                      int quad, int rsw, int l15,
                                      floatx4 acc[2][NT]) {
  constexpr int K = (KC < 16) ? 30 : (62 - 2 * KC);
  waitv2<K>(ap0[KC & 15], ap1[KC & 15]);
  half8 a0 = ap0[KC & 15], a1 = ap1[KC & 15];
  if constexpr (KC < 16) {
    load_sys(ap0[KC], a0p + (KC + 16) * 4);
    load_sys(ap1[KC], a1p + (KC + 16) * 4);
  }
  const int sw = (KC * 4 + quad) ^ rsw;
#pragma unroll
  for (int nt = 0; nt < NT; ++nt) {
    half8 b = w8[(nt * 16 + l15) * 128 + sw];
    acc[0][nt] = __builtin_amdgcn_mfma_f32_16x16x32_f16(a0, b, acc[0][nt], 0, 0, 0);
    acc[1][nt] = __builtin_amdgcn_mfma_f32_16x16x32_f16(a1, b, acc[1][nt], 0, 0, 0);
  }
}

template <int KC, int NT>
__device__ __forceinline__ void krun(const half8* a0p, const half8* a1p,
                                     const half8* __restrict__ w8,
                                     half8 (&ap0)[16], half8 (&ap1)[16],
                                     int quad, int rsw, int l15,
                                     floatx4 acc[2][NT]) {
  if constexpr (KC < 32) {
    kstep<KC, NT>(a0p, a1p, w8, ap0, ap1, quad, rsw, l15, acc);
    krun<KC + 1, NT>(a0p, a1p, w8, ap0, ap1, quad, rsw, l15, acc);
  }
}

template <int NT>
__device__ __forceinline__ void gemm2xNT(const half8* a0p, const half8* a1p,
                                         const half8* __restrict__ w8,
                                         int quad, int rsw, int l15,
                                         floatx4 acc[2][NT]) {
  half8 ap0[16], ap1[16];
#pragma unroll
  for (int i = 0; i < 16; ++i) {
    load_sys(ap0[i], a0p + i * 4);
    load_sys(ap1[i], a1p + i * 4);
  }
  krun<0, NT>(a0p, a1p, w8, ap0, ap1, quad, rsw, l15, acc);
}

__global__ __launch_bounds__(256, 1) void lstm_persist(
    const float* __restrict__ g0,
    const unsigned short* __restrict__ wbuf,
    const float* __restrict__ b_ih, const float* __restrict__ b_hh,
    const float* __restrict__ b_fc,
    float* __restrict__ out,
    unsigned short* __restrict__ hbuf,   // [2][B][H] fp16 double buffer (LLC-coherent)
    unsigned* __restrict__ ctl) {        // flags at ctl+256: 72 x 128B-padded lines
  extern __shared__ __align__(16) unsigned short sW[];   // 128 KiB (gate) / 32 KiB (fc)
  __shared__ __align__(16) unsigned short sH[128 * 16];  // 4 KiB epilogue transpose
  const int tid  = threadIdx.x;
  const int wv   = tid >> 6;
  const int lane = tid & 63;
  const int quad = lane >> 4;
  const int l15  = lane & 15;
  const int bid  = blockIdx.x;
  const bool isg = bid < NGB;
  const int rsw  = l15 & 7;

  unsigned* flags = ctl + 256;
  unsigned* myflag = flags + (size_t)(isg ? bid : 64 + (bid - NGB)) * 32;

  { // stage this block's weight slice into LDS
    const uint4* s4 = (const uint4*)(wbuf +
        (size_t)(isg ? bid * 64 : NGB * 64 + (bid - NGB) * 16) * HH);
    uint4* d4 = (uint4*)sW;
    const int n16 = (isg ? 64 * HH : 16 * HH) / 8;
    for (int i = tid; i < n16; i += 256) d4[i] = s4[i];
  }
  __syncthreads();
  const half8* w8 = (const half8*)sW;
  const floatx4 z4 = {0.f, 0.f, 0.f, 0.f};

  if (isg) {
    const int u = bid * 16 + l15;   // unit this lane owns (all 4 gates)
    const float bi = b_ih[u]          + b_hh[u];
    const float bg = b_ih[2*HH + u]   + b_hh[2*HH + u];
    const float bf = b_ih[HH + u]     + b_hh[HH + u];
    const float bo = b_ih[3*HH + u]   + b_hh[3*HH + u];
    float c[2][4] = {{0, 0, 0, 0}, {0, 0, 0, 0}};

    // ---- t = 0: gates precomputed in g0; c_prev = 0
#pragma unroll
    for (int mt = 0; mt < 2; ++mt)
#pragma unroll
      for (int r = 0; r < 4; ++r) {
        const int m = wv * 32 + mt * 16 + quad * 4 + r;
        const float* gr = g0 + (size_t)m * G4;
        float iv = gr[u], gv = gr[2 * HH + u], ov = gr[3 * HH + u];
        float ct = sigf(iv) * tanhf_fast(gv);
        c[mt][r] = ct;
        store_h(hbuf + (size_t)m * HH + u, sigf(ov) * tanhf_fast(ct));
      }
    vmcnt0();
    __syncthreads();
    if (tid == 0)
      __hip_atomic_fetch_add(myflag, 1u, __ATOMIC_RELAXED, __HIP_MEMORY_SCOPE_AGENT);

    const int aoff0 = (wv * 32 +      l15) * 128 + quad;
    const int aoff1 = (wv * 32 + 16 + l15) * 128 + quad;
    // epilogue bulk-store mapping: thread -> 16B chunk of this block's h slice
    const int em = tid >> 1;                       // m row 0..127
    const int eu = (tid & 1) * 8;                  // u sub-offset 0 / 8

    for (int t = 1; t < TT; ++t) {
      const unsigned s = (unsigned)t;
      poll_flags(flags, s, lane);                  // everyone finished step t-1
      const half8* hb8 = (const half8*)(hbuf + (size_t)((t - 1) & 1) * BB * HH);
      unsigned short* hw = hbuf + (size_t)(t & 1) * BB * HH;

      floatx4 acc[2][4] = {{z4, z4, z4, z4}, {z4, z4, z4, z4}};
      gemm2xNT<4>(hb8 + aoff0, hb8 + aoff1, w8, quad, rsw, l15, acc);

      // cell update -> LDS transpose -> one 16B system store per thread
#pragma unroll
      for (int mt = 0; mt < 2; ++mt)
#pragma unroll
        for (int r = 0; r < 4; ++r) {
          float iv = sigf(acc[mt][0][r] + bi);
          float gv = tanhf_fast(acc[mt][1][r] + bg);
          float fv = sigf(acc[mt][2][r] + bf);
          float ov = sigf(acc[mt][3][r] + bo);
          float ct = fv * c[mt][r] + iv * gv;
          c[mt][r] = ct;
          const int m = wv * 32 + mt * 16 + quad * 4 + r;
          sH[m * 16 + l15] = f2h(ov * tanhf_fast(ct));
        }
      __syncthreads();
      {
        uint4v v = *(const uint4v*)(sH + tid * 8);
        store_sys16(hw + (size_t)em * HH + bid * 16 + eu, v);
      }
      vmcnt0();
      __syncthreads();
      if (tid == 0)
        __hip_atomic_fetch_add(myflag, 1u, __ATOMIC_RELAXED, __HIP_MEMORY_SCOPE_AGENT);
    }
  } else {
    // fc block: y_{t-1} = h_{t-1} @ W_fc^T + b_fc
    const int fb = bid - NGB;
    const int pcol = fb * 16 + l15;
    const float biasf = b_fc[pcol];
    const int aoff0 = ((wv * 2 + 0) * 16 + l15) * 128 + quad;
    const int aoff1 = ((wv * 2 + 1) * 16 + l15) * 128 + quad;

    if (tid == 0)   // h[-1] trivially "read"
      __hip_atomic_fetch_add(myflag, 1u, __ATOMIC_RELAXED, __HIP_MEMORY_SCOPE_AGENT);

    for (int t = 1; t <= TT; ++t) {
      const unsigned s = (unsigned)t;
      poll_flags(flags, s, lane);
      const half8* hb8 = (const half8*)(hbuf + (size_t)((t - 1) & 1) * BB * HH);

      floatx4 acc[2][1] = {{z4}, {z4}};
      gemm2xNT<1>(hb8 + aoff0, hb8 + aoff1, w8, quad, rsw, l15, acc);
#pragma unroll
      for (int mt = 0; mt < 2; ++mt)
#pragma unroll
        for (int r = 0; r < 4; ++r) {
          const int m = wv * 32 + mt * 16 + quad * 4 + r;
          out[(size_t)m * (TT * PP) + (size_t)(t - 1) * PP + pcol] = acc[mt][0][r] + biasf;
        }
      vmcnt0();            // A-loads (and out stores) drained
      __syncthreads();
      if (tid == 0 && t < TT)
        __hip_atomic_fetch_add(myflag, 1u, __ATOMIC_RELAXED, __HIP_MEMORY_SCOPE_AGENT);
    }
  }
}

extern "C" void kernel_launch(void* const* d_in, const int* in_sizes, int n_in,
                              void* d_out, int out_size, void* d_ws, size_t ws_size,
                              hipStream_t stream) {
  const float* z    = (const float*)d_in[1];
  const float* w_ih = (const float*)d_in[2];
  const float* w_hh = (const float*)d_in[3];
  const float* b_ih = (const float*)d_in[4];
  const float* b_hh = (const float*)d_in[5];
  const float* W_fc = (const float*)d_in[6];
  const float* b_fc = (const float*)d_in[7];
  float* out = (float*)d_out;

  // workspace layout (~10.8 MiB)
  char* ws = (char*)d_ws;
  unsigned*       ctl  = (unsigned*)ws;                                   // 16 KiB
  unsigned short* hbuf = (unsigned short*)(ws + 16384);                   // 512 KiB
  float*          g0   = (float*)(ws + 16384 + (size_t)2*BB*HH*2);        // 2 MiB
  unsigned short* wbuf = (unsigned short*)(ws + 16384 + (size_t)2*BB*HH*2
                                              + (size_t)BB*G4*4);         // 8.25 MiB

  (void)hipFuncSetAttribute(reinterpret_cast<const void*>(lstm_persist),
                            hipFuncAttributeMaxDynamicSharedMemorySize, 144 * 1024);

  (void)hipMemsetAsync(ctl, 0, 16384, stream);
  prep_gates0 <<<dim3(G4), dim3(BB), 0, stream>>>(z, w_ih, b_ih, b_hh, g0);
  prep_weights<<<dim3(NGB * 64 + NFB * 16), dim3(256), 0, stream>>>(w_hh, W_fc, wbuf);
  lstm_persist<<<dim3(NB), dim3(256), 128 * 1024, stream>>>(g0, wbuf, b_ih, b_hh, b_fc,
                                                            out, hbuf, ctl);
}